// Round 5
// baseline (144.835 us; speedup 1.0000x reference)
//
#include <hip/hip_runtime.h>
#include <hip/hip_bf16.h>
#include <math.h>

#define IN_C 31
#define OUT_C 31
#define NUM_BASIS 8
#define NPIX 16384
#define UW_OFF 7688
#define RW_OFF 8649
#define PART_OFF (1 << 20)   // byte offset of partial-Y buffer in ws (weights use 620 KB)

typedef __attribute__((ext_vector_type(8))) short bf16x8;
typedef __attribute__((ext_vector_type(4))) float f32x4;

__device__ inline short f2bf(float f) {
    union { __hip_bfloat16 h; short s; } cv;
    cv.h = __float2bfloat16(f);   // RNE
    return cv.s;
}

// ---------------- prep: pack generator weights into MFMA B-fragment chunks ----
// ws layout: for i in [0,31): 20 chunks of 1 KB (20 KB per i, 620 KB total):
//   chunks 0..15 : spline B, chunk = kc*2 + nt  (kc in [0,8), nt in {0,1})
//   chunks 16,17 : uw B (nt 0,1);  chunks 18,19 : rw B (nt 0,1)
__global__ __launch_bounds__(64) void kan_prep_kernel(
    const float* __restrict__ gw, const float* __restrict__ gb,
    unsigned short* __restrict__ ws)
{
    const int blk = blockIdx.x;          // 31*20 = 620
    const int i   = blk / 20;
    const int ch  = blk % 20;
    const int l   = threadIdx.x;
    const int col = l & 15;
    const int krow = l >> 4;
    const int o = (ch & 1) * 16 + col;

    int p;
    if (ch < 16)      p = (i * 31 + o) * 8 + (ch >> 1);
    else if (ch < 18) p = UW_OFF + i * 31 + o;
    else              p = RW_OFF + i * 31 + o;

    bf16x8 v8;
#pragma unroll
    for (int j = 0; j < 8; ++j) {
        const int c = krow * 8 + j;
        float v = 0.f;
        if (o < OUT_C) v = (c < IN_C) ? gw[p * 31 + c] : gb[p];
        v8[j] = f2bf(v);
    }
    ((bf16x8*)ws)[blk * 64 + l] = v8;
}

// ---------------- main: fused generator-GEMM + KAN via MFMA --------------------
// Block = 512 thr = 8 waves, owns 32 pixels (2 M-tiles). gridDim.y=2 splits the
// i-range: block y handles i = y + 2*(w + 8t), t<2 -> 1024 blocks = 4 blocks/CU
// = 32 waves/CU (VGPR capped at 64 via launch_bounds). y=0 writes out, y=1
// writes the partial buffer in ws; a combine kernel sums them.
__global__ __launch_bounds__(512, 8) void kan_mfma_kernel(
    const float* __restrict__ x,               // (31, 16384)
    const unsigned short* __restrict__ wsw,    // packed B fragments
    float* __restrict__ part1,                 // (31, 16384) partial for y=1
    float* __restrict__ out)                   // (31, 16384)
{
    const int t0 = threadIdx.x;
    const int l = t0 & 63;
    const int w = __builtin_amdgcn_readfirstlane(t0 >> 6);  // 0..7
    const int ihalf = blockIdx.y;                            // 0,1
    const int pix0 = blockIdx.x * 32;

    __shared__ float xt[32 * 36];              // x~ tile, stride 36
    __shared__ float yl[32 * 36];              // y accumulator

    for (int idx = t0; idx < 32 * 32; idx += 512) {
        const int n = idx & 31, c = idx >> 5;
        xt[n * 36 + c] = (c < IN_C) ? x[c * NPIX + pix0 + n] : 1.0f;
    }
    for (int idx = t0; idx < 32 * 36; idx += 512) yl[idx] = 0.f;
    __syncthreads();

    // per-lane x~ f32 (8 c-slots) + bf16 A-fragment, both M-tiles
    float xf[2][8];
    bf16x8 ax[2];
#pragma unroll
    for (int mt = 0; mt < 2; ++mt) {
        const int n = mt * 16 + (l & 15);
        const int cb = (l >> 4) * 8;
#pragma unroll
        for (int j = 0; j < 8; ++j) xf[mt][j] = xt[n * 36 + cb + j];
#pragma unroll
        for (int j = 0; j < 8; ++j) ax[mt][j] = f2bf(xf[mt][j]);
    }

    f32x4 Y[2][2];
#pragma unroll
    for (int mt = 0; mt < 2; ++mt)
#pragma unroll
        for (int nt = 0; nt < 2; ++nt) Y[mt][nt] = (f32x4){0.f, 0.f, 0.f, 0.f};

#pragma unroll 1
    for (int tt_i = 0; tt_i < 2; ++tt_i) {
        const int i = ihalf + 2 * (w + 8 * tt_i);
        if (i >= IN_C) break;                  // wave-uniform

        float bas[2][8];
        bf16x8 arw[2];
#pragma unroll
        for (int mt = 0; mt < 2; ++mt) {
            const float xv = xt[(mt * 16 + (l & 15)) * 36 + i];
            const float tt = (xv + 2.2f) * 2.5f;
            const float jf = floorf(tt);
            const float u  = tt - jf;
            const int  jj  = (int)jf;
            const float u2 = u * u, u3 = u2 * u;
            const float n0 = u3 * (1.f / 6.f);
            const float n1 = (-3.f * u3 + 3.f * u2 + 3.f * u + 1.f) * (1.f / 6.f);
            const float n2 = (3.f * u3 - 6.f * u2 + 4.f) * (1.f / 6.f);
            const float omu = 1.f - u;
            const float n3 = omu * omu * omu * (1.f / 6.f);
#pragma unroll
            for (int m = 0; m < 8; ++m) {
                const int d = jj - m;
                bas[mt][m] = (d == 0) ? n0 : (d == 1) ? n1 : (d == 2) ? n2
                           : (d == 3) ? n3 : 0.f;
            }
            const float sil = xv / (1.f + __expf(-xv));
#pragma unroll
            for (int j = 0; j < 8; ++j) arw[mt][j] = f2bf(sil * xf[mt][j]);
        }

        const bf16x8* bw = (const bf16x8*)wsw + (size_t)i * 20 * 64;

        f32x4 SP[2][2], UW[2][2];
#pragma unroll
        for (int mt = 0; mt < 2; ++mt)
#pragma unroll
            for (int nt = 0; nt < 2; ++nt) {
                SP[mt][nt] = (f32x4){0.f, 0.f, 0.f, 0.f};
                UW[mt][nt] = (f32x4){0.f, 0.f, 0.f, 0.f};
            }

        // spline GEMM: K = 256 = 8 kc-chunks; A-frag = bas[kc] * x~
#pragma unroll
        for (int kc = 0; kc < 8; ++kc) {
            const bf16x8 b0 = bw[(kc * 2 + 0) * 64 + l];
            const bf16x8 b1 = bw[(kc * 2 + 1) * 64 + l];
#pragma unroll
            for (int mt = 0; mt < 2; ++mt) {
                bf16x8 af;
#pragma unroll
                for (int j = 0; j < 8; ++j) af[j] = f2bf(bas[mt][kc] * xf[mt][j]);
                SP[mt][0] = __builtin_amdgcn_mfma_f32_16x16x32_bf16(af, b0, SP[mt][0], 0, 0, 0);
                SP[mt][1] = __builtin_amdgcn_mfma_f32_16x16x32_bf16(af, b1, SP[mt][1], 0, 0, 0);
            }
        }
        // uw GEMM (K=32)
        {
            const bf16x8 u0 = bw[16 * 64 + l];
            const bf16x8 u1 = bw[17 * 64 + l];
#pragma unroll
            for (int mt = 0; mt < 2; ++mt) {
                UW[mt][0] = __builtin_amdgcn_mfma_f32_16x16x32_bf16(ax[mt], u0, UW[mt][0], 0, 0, 0);
                UW[mt][1] = __builtin_amdgcn_mfma_f32_16x16x32_bf16(ax[mt], u1, UW[mt][1], 0, 0, 0);
            }
        }
        // rw GEMM (K=32), A = silu*x~, accumulate straight into Y
        {
            const bf16x8 r0 = bw[18 * 64 + l];
            const bf16x8 r1 = bw[19 * 64 + l];
#pragma unroll
            for (int mt = 0; mt < 2; ++mt) {
                Y[mt][0] = __builtin_amdgcn_mfma_f32_16x16x32_bf16(arw[mt], r0, Y[mt][0], 0, 0, 0);
                Y[mt][1] = __builtin_amdgcn_mfma_f32_16x16x32_bf16(arw[mt], r1, Y[mt][1], 0, 0, 0);
            }
        }
        // Y += UW * SP elementwise (identical fragment layout)
#pragma unroll
        for (int mt = 0; mt < 2; ++mt)
#pragma unroll
            for (int nt = 0; nt < 2; ++nt)
#pragma unroll
                for (int r = 0; r < 4; ++r)
                    Y[mt][nt][r] += UW[mt][nt][r] * SP[mt][nt][r];
    }

    // cross-wave reduction: C layout col = l&15 (o), row = (l>>4)*4+r (pixel)
#pragma unroll
    for (int mt = 0; mt < 2; ++mt)
#pragma unroll
        for (int nt = 0; nt < 2; ++nt)
#pragma unroll
            for (int r = 0; r < 4; ++r) {
                const int p = mt * 16 + (l >> 4) * 4 + r;
                const int o = nt * 16 + (l & 15);
                atomicAdd(&yl[p * 36 + o], Y[mt][nt][r]);
            }
    __syncthreads();

    float* dst = (ihalf == 0) ? out : part1;
    for (int idx = t0; idx < 32 * 32; idx += 512) {
        const int n = idx & 31, o = idx >> 5;
        if (o < OUT_C) dst[o * NPIX + pix0 + n] = yl[n * 36 + o];
    }
}

// ---------------- combine: out += part1 (vectorized) --------------------------
__global__ __launch_bounds__(256) void kan_combine_kernel(
    float* __restrict__ out, const float* __restrict__ part1)
{
    const int e = blockIdx.x * 256 + threadIdx.x;   // float4 index
    if (e < (OUT_C * NPIX) / 4) {
        f32x4 a = ((const f32x4*)out)[e];
        f32x4 b = ((const f32x4*)part1)[e];
        a += b;
        ((f32x4*)out)[e] = a;
    }
}

extern "C" void kernel_launch(void* const* d_in, const int* in_sizes, int n_in,
                              void* d_out, int out_size, void* d_ws, size_t ws_size,
                              hipStream_t stream) {
    const float* x  = (const float*)d_in[0];
    const float* gw = (const float*)d_in[1];
    const float* gb = (const float*)d_in[2];
    float* out = (float*)d_out;
    unsigned short* ws = (unsigned short*)d_ws;
    float* part1 = (float*)((char*)d_ws + PART_OFF);

    hipLaunchKernelGGL(kan_prep_kernel, dim3(620), dim3(64), 0, stream, gw, gb, ws);
    hipLaunchKernelGGL(kan_mfma_kernel, dim3(NPIX / 32, 2), dim3(512), 0, stream,
                       x, ws, part1, out);
    const int nv = (OUT_C * NPIX) / 4;                 // 126976
    hipLaunchKernelGGL(kan_combine_kernel, dim3((nv + 255) / 256), dim3(256), 0, stream,
                       out, part1);
}

// Round 6
// 71.609 us; speedup vs baseline: 2.0226x; 2.0226x over previous
//
#include <hip/hip_runtime.h>
#include <hip/hip_bf16.h>
#include <math.h>

#define IN_C 31
#define OUT_C 31
#define NUM_BASIS 8
#define NPIX 16384
#define UW_OFF 7688
#define RW_OFF 8649
#define PART_OFF (1 << 20)   // byte offset of partial-Y buffer in ws (weights use 620 KB)

typedef __attribute__((ext_vector_type(8))) short bf16x8;
typedef __attribute__((ext_vector_type(4))) float f32x4;

__device__ inline short f2bf(float f) {
    union { __hip_bfloat16 h; short s; } cv;
    cv.h = __float2bfloat16(f);   // RNE
    return cv.s;
}

// ---------------- prep: pack generator weights into MFMA B-fragment chunks ----
// ws layout: for i in [0,31): 20 chunks of 1 KB (20 KB per i, 620 KB total):
//   chunks 0..15 : spline B, chunk = kc*2 + nt  (kc in [0,8), nt in {0,1})
//   chunks 16,17 : uw B (nt 0,1);  chunks 18,19 : rw B (nt 0,1)
__global__ __launch_bounds__(64) void kan_prep_kernel(
    const float* __restrict__ gw, const float* __restrict__ gb,
    unsigned short* __restrict__ ws)
{
    const int blk = blockIdx.x;          // 31*20 = 620
    const int i   = blk / 20;
    const int ch  = blk % 20;
    const int l   = threadIdx.x;
    const int col = l & 15;
    const int krow = l >> 4;
    const int o = (ch & 1) * 16 + col;

    int p;
    if (ch < 16)      p = (i * 31 + o) * 8 + (ch >> 1);
    else if (ch < 18) p = UW_OFF + i * 31 + o;
    else              p = RW_OFF + i * 31 + o;

    bf16x8 v8;
#pragma unroll
    for (int j = 0; j < 8; ++j) {
        const int c = krow * 8 + j;
        float v = 0.f;
        if (o < OUT_C) v = (c < IN_C) ? gw[p * 31 + c] : gb[p];
        v8[j] = f2bf(v);
    }
    ((bf16x8*)ws)[blk * 64 + l] = v8;
}

// ---------------- main: fused generator-GEMM + KAN via MFMA --------------------
// Block = 512 thr = 8 waves, owns 32 pixels (2 M-tiles). gridDim.y=2 splits the
// i-range: block y handles i = y + 2*(w + 8t), t<2 -> 1024 blocks. y=0 writes
// out, y=1 writes the partial buffer in ws; a combine kernel sums them.
// NOTE: launch_bounds kept at (512,2): (512,8) capped VGPRs at 32 and spilled
// 550 MB to scratch (round-5 regression). VGPR=64 is this kernel's natural fit.
__global__ __launch_bounds__(512, 2) void kan_mfma_kernel(
    const float* __restrict__ x,               // (31, 16384)
    const unsigned short* __restrict__ wsw,    // packed B fragments
    float* __restrict__ part1,                 // (31, 16384) partial for y=1
    float* __restrict__ out)                   // (31, 16384)
{
    const int t0 = threadIdx.x;
    const int l = t0 & 63;
    const int w = __builtin_amdgcn_readfirstlane(t0 >> 6);  // 0..7
    const int ihalf = blockIdx.y;                            // 0,1
    const int pix0 = blockIdx.x * 32;

    __shared__ float xt[32 * 36];              // x~ tile, stride 36
    __shared__ float yl[32 * 36];              // y accumulator

    for (int idx = t0; idx < 32 * 32; idx += 512) {
        const int n = idx & 31, c = idx >> 5;
        xt[n * 36 + c] = (c < IN_C) ? x[c * NPIX + pix0 + n] : 1.0f;
    }
    for (int idx = t0; idx < 32 * 36; idx += 512) yl[idx] = 0.f;
    __syncthreads();

    // per-lane x~ f32 (8 c-slots) + bf16 A-fragment, both M-tiles
    float xf[2][8];
    bf16x8 ax[2];
#pragma unroll
    for (int mt = 0; mt < 2; ++mt) {
        const int n = mt * 16 + (l & 15);
        const int cb = (l >> 4) * 8;
#pragma unroll
        for (int j = 0; j < 8; ++j) xf[mt][j] = xt[n * 36 + cb + j];
#pragma unroll
        for (int j = 0; j < 8; ++j) ax[mt][j] = f2bf(xf[mt][j]);
    }

    f32x4 Y[2][2];
#pragma unroll
    for (int mt = 0; mt < 2; ++mt)
#pragma unroll
        for (int nt = 0; nt < 2; ++nt) Y[mt][nt] = (f32x4){0.f, 0.f, 0.f, 0.f};

#pragma unroll 1
    for (int tt_i = 0; tt_i < 2; ++tt_i) {
        const int i = ihalf + 2 * (w + 8 * tt_i);
        if (i >= IN_C) break;                  // wave-uniform

        float bas[2][8];
        bf16x8 arw[2];
#pragma unroll
        for (int mt = 0; mt < 2; ++mt) {
            const float xv = xt[(mt * 16 + (l & 15)) * 36 + i];
            const float tt = (xv + 2.2f) * 2.5f;
            const float jf = floorf(tt);
            const float u  = tt - jf;
            const int  jj  = (int)jf;
            const float u2 = u * u, u3 = u2 * u;
            const float n0 = u3 * (1.f / 6.f);
            const float n1 = (-3.f * u3 + 3.f * u2 + 3.f * u + 1.f) * (1.f / 6.f);
            const float n2 = (3.f * u3 - 6.f * u2 + 4.f) * (1.f / 6.f);
            const float omu = 1.f - u;
            const float n3 = omu * omu * omu * (1.f / 6.f);
#pragma unroll
            for (int m = 0; m < 8; ++m) {
                const int d = jj - m;
                bas[mt][m] = (d == 0) ? n0 : (d == 1) ? n1 : (d == 2) ? n2
                           : (d == 3) ? n3 : 0.f;
            }
            const float sil = xv / (1.f + __expf(-xv));
#pragma unroll
            for (int j = 0; j < 8; ++j) arw[mt][j] = f2bf(sil * xf[mt][j]);
        }

        const bf16x8* bw = (const bf16x8*)wsw + (size_t)i * 20 * 64;

        f32x4 SP[2][2], UW[2][2];
#pragma unroll
        for (int mt = 0; mt < 2; ++mt)
#pragma unroll
            for (int nt = 0; nt < 2; ++nt) {
                SP[mt][nt] = (f32x4){0.f, 0.f, 0.f, 0.f};
                UW[mt][nt] = (f32x4){0.f, 0.f, 0.f, 0.f};
            }

        // spline GEMM: K = 256 = 8 kc-chunks; A-frag = bas[kc] * x~
#pragma unroll
        for (int kc = 0; kc < 8; ++kc) {
            const bf16x8 b0 = bw[(kc * 2 + 0) * 64 + l];
            const bf16x8 b1 = bw[(kc * 2 + 1) * 64 + l];
#pragma unroll
            for (int mt = 0; mt < 2; ++mt) {
                bf16x8 af;
#pragma unroll
                for (int j = 0; j < 8; ++j) af[j] = f2bf(bas[mt][kc] * xf[mt][j]);
                SP[mt][0] = __builtin_amdgcn_mfma_f32_16x16x32_bf16(af, b0, SP[mt][0], 0, 0, 0);
                SP[mt][1] = __builtin_amdgcn_mfma_f32_16x16x32_bf16(af, b1, SP[mt][1], 0, 0, 0);
            }
        }
        // uw GEMM (K=32)
        {
            const bf16x8 u0 = bw[16 * 64 + l];
            const bf16x8 u1 = bw[17 * 64 + l];
#pragma unroll
            for (int mt = 0; mt < 2; ++mt) {
                UW[mt][0] = __builtin_amdgcn_mfma_f32_16x16x32_bf16(ax[mt], u0, UW[mt][0], 0, 0, 0);
                UW[mt][1] = __builtin_amdgcn_mfma_f32_16x16x32_bf16(ax[mt], u1, UW[mt][1], 0, 0, 0);
            }
        }
        // rw GEMM (K=32), A = silu*x~, accumulate straight into Y
        {
            const bf16x8 r0 = bw[18 * 64 + l];
            const bf16x8 r1 = bw[19 * 64 + l];
#pragma unroll
            for (int mt = 0; mt < 2; ++mt) {
                Y[mt][0] = __builtin_amdgcn_mfma_f32_16x16x32_bf16(arw[mt], r0, Y[mt][0], 0, 0, 0);
                Y[mt][1] = __builtin_amdgcn_mfma_f32_16x16x32_bf16(arw[mt], r1, Y[mt][1], 0, 0, 0);
            }
        }
        // Y += UW * SP elementwise (identical fragment layout)
#pragma unroll
        for (int mt = 0; mt < 2; ++mt)
#pragma unroll
            for (int nt = 0; nt < 2; ++nt)
#pragma unroll
                for (int r = 0; r < 4; ++r)
                    Y[mt][nt][r] += UW[mt][nt][r] * SP[mt][nt][r];
    }

    // cross-wave reduction: C layout col = l&15 (o), row = (l>>4)*4+r (pixel)
#pragma unroll
    for (int mt = 0; mt < 2; ++mt)
#pragma unroll
        for (int nt = 0; nt < 2; ++nt)
#pragma unroll
            for (int r = 0; r < 4; ++r) {
                const int p = mt * 16 + (l >> 4) * 4 + r;
                const int o = nt * 16 + (l & 15);
                atomicAdd(&yl[p * 36 + o], Y[mt][nt][r]);
            }
    __syncthreads();

    float* dst = (ihalf == 0) ? out : part1;
    for (int idx = t0; idx < 32 * 32; idx += 512) {
        const int n = idx & 31, o = idx >> 5;
        if (o < OUT_C) dst[o * NPIX + pix0 + n] = yl[n * 36 + o];
    }
}

// ---------------- combine: out += part1 (vectorized) --------------------------
__global__ __launch_bounds__(256) void kan_combine_kernel(
    float* __restrict__ out, const float* __restrict__ part1)
{
    const int e = blockIdx.x * 256 + threadIdx.x;   // float4 index
    if (e < (OUT_C * NPIX) / 4) {
        f32x4 a = ((const f32x4*)out)[e];
        f32x4 b = ((const f32x4*)part1)[e];
        a += b;
        ((f32x4*)out)[e] = a;
    }
}

extern "C" void kernel_launch(void* const* d_in, const int* in_sizes, int n_in,
                              void* d_out, int out_size, void* d_ws, size_t ws_size,
                              hipStream_t stream) {
    const float* x  = (const float*)d_in[0];
    const float* gw = (const float*)d_in[1];
    const float* gb = (const float*)d_in[2];
    float* out = (float*)d_out;
    unsigned short* ws = (unsigned short*)d_ws;
    float* part1 = (float*)((char*)d_ws + PART_OFF);

    hipLaunchKernelGGL(kan_prep_kernel, dim3(620), dim3(64), 0, stream, gw, gb, ws);
    hipLaunchKernelGGL(kan_mfma_kernel, dim3(NPIX / 32, 2), dim3(512), 0, stream,
                       x, ws, part1, out);
    const int nv = (OUT_C * NPIX) / 4;                 // 126976
    hipLaunchKernelGGL(kan_combine_kernel, dim3((nv + 255) / 256), dim3(256), 0, stream,
                       out, part1);
}

// Round 7
// 49.703 us; speedup vs baseline: 2.9140x; 1.4408x over previous
//
#include <hip/hip_runtime.h>
#include <hip/hip_bf16.h>
#include <math.h>

#define IN_C 31
#define OUT_C 31
#define NPIX 16384
#define UW_OFF 7688
#define RW_OFF 8649
#define PART_OFF (1 << 20)    // ws byte offset of partial-Y buffers (weights use 620 KB)
#define CHUNK_BYTES 20480     // 20 KB of packed B-fragments per input channel i

typedef __attribute__((ext_vector_type(8))) short bf16x8;
typedef __attribute__((ext_vector_type(4))) float f32x4;

__device__ inline short f2bf(float f) {
    union { __hip_bfloat16 h; short s; } cv;
    cv.h = __float2bfloat16(f);   // RNE
    return cv.s;
}

// ---------------- prep: pack generator weights into MFMA B-fragment chunks ----
// ws layout: for i in [0,31): 20 chunks of 1 KB (20 KB per i, 620 KB total):
//   chunks 0..15 : spline B, chunk = kc*2 + nt  (kc in [0,8), nt in {0,1})
//   chunks 16,17 : uw B (nt 0,1);  chunks 18,19 : rw B (nt 0,1)
__global__ __launch_bounds__(64) void kan_prep_kernel(
    const float* __restrict__ gw, const float* __restrict__ gb,
    unsigned short* __restrict__ ws)
{
    const int blk = blockIdx.x;          // 31*20 = 620
    const int i   = blk / 20;
    const int ch  = blk % 20;
    const int l   = threadIdx.x;
    const int col = l & 15;
    const int krow = l >> 4;
    const int o = (ch & 1) * 16 + col;

    int p;
    if (ch < 16)      p = (i * 31 + o) * 8 + (ch >> 1);
    else if (ch < 18) p = UW_OFF + i * 31 + o;
    else              p = RW_OFF + i * 31 + o;

    bf16x8 v8;
#pragma unroll
    for (int j = 0; j < 8; ++j) {
        const int c = krow * 8 + j;
        float v = 0.f;
        if (o < OUT_C) v = (c < IN_C) ? gw[p * 31 + c] : gb[p];
        v8[j] = f2bf(v);
    }
    ((bf16x8*)ws)[blk * 64 + l] = v8;
}

// Stage one i's 20 KB chunk into LDS via async global->LDS DMA (linear both
// sides: slot s -> byte s*16 in both global chunk and LDS buffer).
__device__ __forceinline__ void stage_i(const unsigned char* wsrc,
                                        unsigned char* ldst, int t) {
#pragma unroll
    for (int k = 0; k < 5; ++k) {
        const int off = (k * 256 + t) * 16;
        __builtin_amdgcn_global_load_lds(
            (const __attribute__((address_space(1))) unsigned int*)(wsrc + off),
            (__attribute__((address_space(3))) unsigned int*)(ldst + off),
            16, 0, 0);
    }
}

// ---------------- main: LDS-shared weights, waves share i ----------------------
// Block = 256 thr = 4 waves; wave w owns 2 M-tiles (32 px) at n0 = w*32; block
// covers 128 px. All waves process the SAME i; weights staged once per block
// per i into a 2x20KB LDS double buffer. gridDim.y=4 splits i into 8/8/8/7.
// y=0 writes out, y=1..3 write partial buffers; combine kernel sums.
__global__ __launch_bounds__(256) void kan_mfma3_kernel(
    const float* __restrict__ x,               // (31, 16384)
    const unsigned char* __restrict__ wsw,     // packed B fragments (bytes)
    float* __restrict__ parts,                 // 3 x (31,16384) partials
    float* __restrict__ out)                   // (31, 16384)
{
    const int t = threadIdx.x;
    const int l = t & 63;
    const int w = t >> 6;                      // 0..3
    const int pix0 = blockIdx.x * 128;
    const int ihalf = blockIdx.y;              // 0..3
    const int ibase = ihalf * 8;
    const int ni = (ihalf == 3) ? 7 : 8;

    __shared__ __align__(16) unsigned char wlds[2][CHUNK_BYTES]; // 40 KB
    __shared__ float xy[128 * 33];             // x~ tile during loop; Y after

    // prologue: stage first i chunk + x~ tile
    stage_i(wsw + (size_t)ibase * CHUNK_BYTES, wlds[0], t);
    for (int idx = t; idx < 128 * 32; idx += 256) {
        const int n = idx & 127, c = idx >> 7;
        xy[n * 33 + c] = (c < IN_C) ? x[c * NPIX + pix0 + n] : 1.0f;
    }
    __syncthreads();   // drains vmcnt (DMA done) + xt visible

    const int n0 = w * 32;
    float xf[2][8];
    bf16x8 ax[2];
#pragma unroll
    for (int mt = 0; mt < 2; ++mt) {
        const int row = n0 + mt * 16 + (l & 15);
        const int cb = (l >> 4) * 8;
#pragma unroll
        for (int j = 0; j < 8; ++j) xf[mt][j] = xy[row * 33 + cb + j];
#pragma unroll
        for (int j = 0; j < 8; ++j) ax[mt][j] = f2bf(xf[mt][j]);
    }

    f32x4 Y[2][2];
#pragma unroll
    for (int mt = 0; mt < 2; ++mt)
#pragma unroll
        for (int nt = 0; nt < 2; ++nt) Y[mt][nt] = (f32x4){0.f, 0.f, 0.f, 0.f};

#pragma unroll 1
    for (int tt_i = 0; tt_i < 8; ++tt_i) {
        if (tt_i >= ni) break;
        const int i = ibase + tt_i;

        // prefetch next i's weights into the other buffer
        if (tt_i + 1 < ni)
            stage_i(wsw + (size_t)(i + 1) * CHUNK_BYTES, wlds[(tt_i + 1) & 1], t);

        const unsigned char* wb = wlds[tt_i & 1];

        // ---- basis (uniform cardinal cubic) + silu*x~ fragment, per M-tile ----
        float bas[2][8];
        bf16x8 arw[2];
#pragma unroll
        for (int mt = 0; mt < 2; ++mt) {
            const float xv = xy[(n0 + mt * 16 + (l & 15)) * 33 + i];
            const float tb = (xv + 2.2f) * 2.5f;
            const float jf = floorf(tb);
            const float u  = tb - jf;
            const int  jj  = (int)jf;
            const float u2 = u * u, u3 = u2 * u;
            const float b0v = u3 * (1.f / 6.f);
            const float b1v = (-3.f * u3 + 3.f * u2 + 3.f * u + 1.f) * (1.f / 6.f);
            const float b2v = (3.f * u3 - 6.f * u2 + 4.f) * (1.f / 6.f);
            const float omu = 1.f - u;
            const float b3v = omu * omu * omu * (1.f / 6.f);
#pragma unroll
            for (int m = 0; m < 8; ++m) {
                const int d = jj - m;
                bas[mt][m] = (d == 0) ? b0v : (d == 1) ? b1v : (d == 2) ? b2v
                           : (d == 3) ? b3v : 0.f;
            }
            const float sil = xv / (1.f + __expf(-xv));
#pragma unroll
            for (int j = 0; j < 8; ++j) arw[mt][j] = f2bf(sil * xf[mt][j]);
        }

        f32x4 SP[2][2], UW[2][2];
#pragma unroll
        for (int mt = 0; mt < 2; ++mt)
#pragma unroll
            for (int nt = 0; nt < 2; ++nt) {
                SP[mt][nt] = (f32x4){0.f, 0.f, 0.f, 0.f};
                UW[mt][nt] = (f32x4){0.f, 0.f, 0.f, 0.f};
            }

        // ---- spline GEMM: 8 kc chunks; A-frag = bas[kc] * x~ (from LDS B) ----
#pragma unroll
        for (int kc = 0; kc < 8; ++kc) {
            const bf16x8 b0 = *(const bf16x8*)(wb + ((kc * 2 + 0) * 64 + l) * 16);
            const bf16x8 b1 = *(const bf16x8*)(wb + ((kc * 2 + 1) * 64 + l) * 16);
#pragma unroll
            for (int mt = 0; mt < 2; ++mt) {
                bf16x8 af;
#pragma unroll
                for (int j = 0; j < 8; ++j) af[j] = f2bf(bas[mt][kc] * xf[mt][j]);
                SP[mt][0] = __builtin_amdgcn_mfma_f32_16x16x32_bf16(af, b0, SP[mt][0], 0, 0, 0);
                SP[mt][1] = __builtin_amdgcn_mfma_f32_16x16x32_bf16(af, b1, SP[mt][1], 0, 0, 0);
            }
        }
        // ---- uw GEMM (K=32) ----
        {
            const bf16x8 u0 = *(const bf16x8*)(wb + (16 * 64 + l) * 16);
            const bf16x8 u1 = *(const bf16x8*)(wb + (17 * 64 + l) * 16);
#pragma unroll
            for (int mt = 0; mt < 2; ++mt) {
                UW[mt][0] = __builtin_amdgcn_mfma_f32_16x16x32_bf16(ax[mt], u0, UW[mt][0], 0, 0, 0);
                UW[mt][1] = __builtin_amdgcn_mfma_f32_16x16x32_bf16(ax[mt], u1, UW[mt][1], 0, 0, 0);
            }
        }
        // ---- rw GEMM (K=32), A = silu*x~, accumulate straight into Y ----
        {
            const bf16x8 r0 = *(const bf16x8*)(wb + (18 * 64 + l) * 16);
            const bf16x8 r1 = *(const bf16x8*)(wb + (19 * 64 + l) * 16);
#pragma unroll
            for (int mt = 0; mt < 2; ++mt) {
                Y[mt][0] = __builtin_amdgcn_mfma_f32_16x16x32_bf16(arw[mt], r0, Y[mt][0], 0, 0, 0);
                Y[mt][1] = __builtin_amdgcn_mfma_f32_16x16x32_bf16(arw[mt], r1, Y[mt][1], 0, 0, 0);
            }
        }
        // ---- Y += UW * SP (identical fragment layout) ----
#pragma unroll
        for (int mt = 0; mt < 2; ++mt)
#pragma unroll
            for (int nt = 0; nt < 2; ++nt)
#pragma unroll
                for (int r = 0; r < 4; ++r)
                    Y[mt][nt][r] += UW[mt][nt][r] * SP[mt][nt][r];

        __syncthreads();   // DMA for i+1 done; all waves finished reading wb
    }

    // ---- gather Y into LDS (reuse xy) for coalesced store ----
    // C layout: col(o) = l&15, row(px) = (l>>4)*4 + r. Each (px,o) has one owner.
#pragma unroll
    for (int mt = 0; mt < 2; ++mt)
#pragma unroll
        for (int nt = 0; nt < 2; ++nt)
#pragma unroll
            for (int r = 0; r < 4; ++r) {
                const int p = n0 + mt * 16 + (l >> 4) * 4 + r;
                const int o = nt * 16 + (l & 15);
                if (o < OUT_C) xy[p * 33 + o] = Y[mt][nt][r];
            }
    __syncthreads();

    float* dst = (ihalf == 0) ? out : (parts + (size_t)(ihalf - 1) * OUT_C * NPIX);
    for (int idx = t; idx < 128 * OUT_C; idx += 256) {
        const int n = idx & 127, o = idx >> 7;
        dst[o * NPIX + pix0 + n] = xy[n * 33 + o];
    }
}

// ---------------- combine: out += p0 + p1 + p2 (vectorized) -------------------
__global__ __launch_bounds__(256) void kan_combine_kernel(
    float* __restrict__ out, const float* __restrict__ parts)
{
    const int e = blockIdx.x * 256 + threadIdx.x;   // float4 index
    const int nv = (OUT_C * NPIX) / 4;
    if (e < nv) {
        f32x4 a = ((const f32x4*)out)[e];
        a += ((const f32x4*)parts)[e];
        a += ((const f32x4*)parts)[e + nv];
        a += ((const f32x4*)parts)[e + 2 * nv];
        ((f32x4*)out)[e] = a;
    }
}

extern "C" void kernel_launch(void* const* d_in, const int* in_sizes, int n_in,
                              void* d_out, int out_size, void* d_ws, size_t ws_size,
                              hipStream_t stream) {
    const float* x  = (const float*)d_in[0];
    const float* gw = (const float*)d_in[1];
    const float* gb = (const float*)d_in[2];
    float* out = (float*)d_out;
    unsigned short* ws = (unsigned short*)d_ws;
    float* parts = (float*)((char*)d_ws + PART_OFF);   // 3 x 2 MB

    hipLaunchKernelGGL(kan_prep_kernel, dim3(620), dim3(64), 0, stream, gw, gb, ws);
    hipLaunchKernelGGL(kan_mfma3_kernel, dim3(NPIX / 128, 4), dim3(256), 0, stream,
                       x, (const unsigned char*)d_ws, parts, out);
    const int nv = (OUT_C * NPIX) / 4;                 // 126976
    hipLaunchKernelGGL(kan_combine_kernel, dim3((nv + 255) / 256), dim3(256), 0, stream,
                       out, parts);
}

// Round 8
// 46.784 us; speedup vs baseline: 3.0958x; 1.0624x over previous
//
#include <hip/hip_runtime.h>
#include <hip/hip_bf16.h>
#include <math.h>

#define IN_C 31
#define OUT_C 31
#define NPIX 16384
#define UW_OFF 7688
#define RW_OFF 8649
#define PART_OFF (640 * 1024)  // ws byte offset of partial-Y buffers (weights use 620 KB)
#define CHUNK_BYTES 20480      // 20 KB of packed B-fragments per input channel i

typedef __attribute__((ext_vector_type(8))) short bf16x8;
typedef __attribute__((ext_vector_type(4))) float f32x4;

__device__ inline short f2bf(float f) {
    union { __hip_bfloat16 h; short s; } cv;
    cv.h = __float2bfloat16(f);   // RNE
    return cv.s;
}

// ---------------- prep: pack generator weights into MFMA B-fragment chunks ----
// ws layout: for i in [0,31): 20 chunks of 1 KB (20 KB per i, 620 KB total):
//   chunks 0..15 : spline B, chunk = kc*2 + nt  (kc in [0,8), nt in {0,1})
//   chunks 16,17 : uw B (nt 0,1);  chunks 18,19 : rw B (nt 0,1)
__global__ __launch_bounds__(64) void kan_prep_kernel(
    const float* __restrict__ gw, const float* __restrict__ gb,
    unsigned short* __restrict__ ws)
{
    const int blk = blockIdx.x;          // 31*20 = 620
    const int i   = blk / 20;
    const int ch  = blk % 20;
    const int l   = threadIdx.x;
    const int col = l & 15;
    const int krow = l >> 4;
    const int o = (ch & 1) * 16 + col;

    int p;
    if (ch < 16)      p = (i * 31 + o) * 8 + (ch >> 1);
    else if (ch < 18) p = UW_OFF + i * 31 + o;
    else              p = RW_OFF + i * 31 + o;

    bf16x8 v8;
#pragma unroll
    for (int j = 0; j < 8; ++j) {
        const int c = krow * 8 + j;
        float v = 0.f;
        if (o < OUT_C) v = (c < IN_C) ? gw[p * 31 + c] : gb[p];
        v8[j] = f2bf(v);
    }
    ((bf16x8*)ws)[blk * 64 + l] = v8;
}

// Stage one i's 20 KB chunk into LDS via async global->LDS DMA (linear both
// sides: slot s -> byte s*16 in both global chunk and LDS buffer).
__device__ __forceinline__ void stage_i(const unsigned char* wsrc,
                                        unsigned char* ldst, int t) {
#pragma unroll
    for (int k = 0; k < 5; ++k) {
        const int off = (k * 256 + t) * 16;
        __builtin_amdgcn_global_load_lds(
            (const __attribute__((address_space(1))) unsigned int*)(wsrc + off),
            (__attribute__((address_space(3))) unsigned int*)(ldst + off),
            16, 0, 0);
    }
}

// ---------------- main: single-buffer LDS weights, high occupancy -------------
// Block = 256 thr = 4 waves x 32 px (2 M-tiles each) = 128 px. All waves share
// the SAME i; 20 KB weight chunk staged once per block per i (single buffer;
// stage latency hidden by co-resident blocks). gridDim.y = nsplit (8 if ws
// allows, else 4) splits the i-range -> 1024 blocks = 4 blocks/CU = 16
// waves/CU. LDS = 20 KB + 16.9 KB = 36.9 KB (4 blocks/CU). VGPR capped 128 via
// launch_bounds(256,4). y=0 writes out; y>0 writes partials; combine sums.
__global__ __launch_bounds__(256, 4) void kan_mfma4_kernel(
    const float* __restrict__ x,               // (31, 16384)
    const unsigned char* __restrict__ wsw,     // packed B fragments (bytes)
    float* __restrict__ parts,                 // (nsplit-1) x (31,16384)
    float* __restrict__ out,                   // (31, 16384)
    int nsplit)
{
    const int t = threadIdx.x;
    const int l = t & 63;
    const int w = t >> 6;                      // 0..3
    const int pix0 = blockIdx.x * 128;
    const int csize = (IN_C + nsplit - 1) / nsplit;
    const int ibase = blockIdx.y * csize;
    const int ni = min(csize, IN_C - ibase);

    __shared__ __align__(16) unsigned char wlds[CHUNK_BYTES];  // 20 KB, reused for Y
    __shared__ float xy[128 * 33];                             // x~ tile (16.9 KB)

    // prologue: x~ tile (c==31 -> 1.0)
    for (int idx = t; idx < 128 * 32; idx += 256) {
        const int n = idx & 127, c = idx >> 7;
        xy[n * 33 + c] = (c < IN_C) ? x[c * NPIX + pix0 + n] : 1.0f;
    }

    const int n0 = w * 32;
    float xf[2][8];
    bf16x8 ax[2];

    f32x4 Y[2][2];
#pragma unroll
    for (int mt = 0; mt < 2; ++mt)
#pragma unroll
        for (int nt = 0; nt < 2; ++nt) Y[mt][nt] = (f32x4){0.f, 0.f, 0.f, 0.f};

    bool first = true;

#pragma unroll 1
    for (int tt_i = 0; tt_i < ni; ++tt_i) {
        const int i = ibase + tt_i;

        // stage this i's weights (prev iter's trailing barrier guarantees all
        // waves are done reading the buffer)
        stage_i(wsw + (size_t)i * CHUNK_BYTES, wlds, t);
        __syncthreads();   // drains vmcnt (DMA done); also covers x~ visibility

        if (first) {       // after first barrier: x~ is visible, load registers
            first = false;
#pragma unroll
            for (int mt = 0; mt < 2; ++mt) {
                const int row = n0 + mt * 16 + (l & 15);
                const int cb = (l >> 4) * 8;
#pragma unroll
                for (int j = 0; j < 8; ++j) xf[mt][j] = xy[row * 33 + cb + j];
#pragma unroll
                for (int j = 0; j < 8; ++j) ax[mt][j] = f2bf(xf[mt][j]);
            }
        }

        const unsigned char* wb = wlds;

        // ---- basis (uniform cardinal cubic) + silu*x~ fragment, per M-tile ----
        float bas[2][8];
        bf16x8 arw[2];
#pragma unroll
        for (int mt = 0; mt < 2; ++mt) {
            const float xv = xy[(n0 + mt * 16 + (l & 15)) * 33 + i];
            const float tb = (xv + 2.2f) * 2.5f;
            const float jf = floorf(tb);
            const float u  = tb - jf;
            const int  jj  = (int)jf;
            const float u2 = u * u, u3 = u2 * u;
            const float b0v = u3 * (1.f / 6.f);
            const float b1v = (-3.f * u3 + 3.f * u2 + 3.f * u + 1.f) * (1.f / 6.f);
            const float b2v = (3.f * u3 - 6.f * u2 + 4.f) * (1.f / 6.f);
            const float omu = 1.f - u;
            const float b3v = omu * omu * omu * (1.f / 6.f);
#pragma unroll
            for (int m = 0; m < 8; ++m) {
                const int d = jj - m;
                bas[mt][m] = (d == 0) ? b0v : (d == 1) ? b1v : (d == 2) ? b2v
                           : (d == 3) ? b3v : 0.f;
            }
            const float sil = xv / (1.f + __expf(-xv));
#pragma unroll
            for (int j = 0; j < 8; ++j) arw[mt][j] = f2bf(sil * xf[mt][j]);
        }

        f32x4 SP[2][2], UW[2][2];
#pragma unroll
        for (int mt = 0; mt < 2; ++mt)
#pragma unroll
            for (int nt = 0; nt < 2; ++nt) {
                SP[mt][nt] = (f32x4){0.f, 0.f, 0.f, 0.f};
                UW[mt][nt] = (f32x4){0.f, 0.f, 0.f, 0.f};
            }

        // ---- spline GEMM: 8 kc chunks; A-frag = bas[kc] * x~ (B from LDS) ----
#pragma unroll
        for (int kc = 0; kc < 8; ++kc) {
            const bf16x8 b0 = *(const bf16x8*)(wb + ((kc * 2 + 0) * 64 + l) * 16);
            const bf16x8 b1 = *(const bf16x8*)(wb + ((kc * 2 + 1) * 64 + l) * 16);
#pragma unroll
            for (int mt = 0; mt < 2; ++mt) {
                bf16x8 af;
#pragma unroll
                for (int j = 0; j < 8; ++j) af[j] = f2bf(bas[mt][kc] * xf[mt][j]);
                SP[mt][0] = __builtin_amdgcn_mfma_f32_16x16x32_bf16(af, b0, SP[mt][0], 0, 0, 0);
                SP[mt][1] = __builtin_amdgcn_mfma_f32_16x16x32_bf16(af, b1, SP[mt][1], 0, 0, 0);
            }
        }
        // ---- uw GEMM (K=32) ----
        {
            const bf16x8 u0 = *(const bf16x8*)(wb + (16 * 64 + l) * 16);
            const bf16x8 u1 = *(const bf16x8*)(wb + (17 * 64 + l) * 16);
#pragma unroll
            for (int mt = 0; mt < 2; ++mt) {
                UW[mt][0] = __builtin_amdgcn_mfma_f32_16x16x32_bf16(ax[mt], u0, UW[mt][0], 0, 0, 0);
                UW[mt][1] = __builtin_amdgcn_mfma_f32_16x16x32_bf16(ax[mt], u1, UW[mt][1], 0, 0, 0);
            }
        }
        // ---- rw GEMM (K=32), A = silu*x~, accumulate straight into Y ----
        {
            const bf16x8 r0 = *(const bf16x8*)(wb + (18 * 64 + l) * 16);
            const bf16x8 r1 = *(const bf16x8*)(wb + (19 * 64 + l) * 16);
#pragma unroll
            for (int mt = 0; mt < 2; ++mt) {
                Y[mt][0] = __builtin_amdgcn_mfma_f32_16x16x32_bf16(arw[mt], r0, Y[mt][0], 0, 0, 0);
                Y[mt][1] = __builtin_amdgcn_mfma_f32_16x16x32_bf16(arw[mt], r1, Y[mt][1], 0, 0, 0);
            }
        }
        // ---- Y += UW * SP (identical fragment layout) ----
#pragma unroll
        for (int mt = 0; mt < 2; ++mt)
#pragma unroll
            for (int nt = 0; nt < 2; ++nt)
#pragma unroll
                for (int r = 0; r < 4; ++r)
                    Y[mt][nt][r] += UW[mt][nt][r] * SP[mt][nt][r];

        __syncthreads();   // all waves done reading wlds before next stage
    }

    // ---- gather Y into wlds (free now) for coalesced store ----
    float* yb = (float*)wlds;   // 128*33 floats = 16.9 KB <= 20 KB
#pragma unroll
    for (int mt = 0; mt < 2; ++mt)
#pragma unroll
        for (int nt = 0; nt < 2; ++nt)
#pragma unroll
            for (int r = 0; r < 4; ++r) {
                const int p = n0 + mt * 16 + (l >> 4) * 4 + r;
                const int o = nt * 16 + (l & 15);
                if (o < OUT_C) yb[p * 33 + o] = Y[mt][nt][r];
            }
    __syncthreads();

    float* dst = (blockIdx.y == 0) ? out
               : (parts + (size_t)(blockIdx.y - 1) * OUT_C * NPIX);
    for (int idx = t; idx < 128 * OUT_C; idx += 256) {
        const int n = idx & 127, o = idx >> 7;
        dst[o * NPIX + pix0 + n] = yb[n * 33 + o];
    }
}

// ---------------- combine: out += sum of npart partials (vectorized) ----------
__global__ __launch_bounds__(256) void kan_combine_kernel(
    float* __restrict__ out, const float* __restrict__ parts, int npart)
{
    const int e = blockIdx.x * 256 + threadIdx.x;   // float4 index
    const int nv = (OUT_C * NPIX) / 4;
    if (e < nv) {
        f32x4 a = ((const f32x4*)out)[e];
        for (int j = 0; j < npart; ++j)
            a += ((const f32x4*)parts)[e + (size_t)j * nv];
        ((f32x4*)out)[e] = a;
    }
}

extern "C" void kernel_launch(void* const* d_in, const int* in_sizes, int n_in,
                              void* d_out, int out_size, void* d_ws, size_t ws_size,
                              hipStream_t stream) {
    const float* x  = (const float*)d_in[0];
    const float* gw = (const float*)d_in[1];
    const float* gb = (const float*)d_in[2];
    float* out = (float*)d_out;
    unsigned short* ws = (unsigned short*)d_ws;
    float* parts = (float*)((char*)d_ws + PART_OFF);

    // 8-way i-split needs 7 f32 partials (14.2 MB); fall back to 4-way if ws
    // is too small (deterministic: depends only on ws_size).
    const size_t part_bytes = (size_t)OUT_C * NPIX * 4;
    const int nsplit = (ws_size >= PART_OFF + 7 * part_bytes) ? 8 : 4;

    hipLaunchKernelGGL(kan_prep_kernel, dim3(620), dim3(64), 0, stream, gw, gb, ws);
    hipLaunchKernelGGL(kan_mfma4_kernel, dim3(NPIX / 128, nsplit), dim3(256), 0, stream,
                       x, (const unsigned char*)d_ws, parts, out, nsplit);
    const int nv = (OUT_C * NPIX) / 4;                 // 126976
    hipLaunchKernelGGL(kan_combine_kernel, dim3((nv + 255) / 256), dim3(256), 0, stream,
                       out, parts, nsplit - 1);
}